// Round 7
// baseline (150.399 us; speedup 1.0000x reference)
//
#include <hip/hip_runtime.h>
#include <hip/hip_bf16.h>

// PositionalBias: pbv[n,j,h,d] = sum_{l=1..2046} w[h,|j-l|] * v[n,l,h,d]  (j in 1..2046, else 0)
//                 z_pb[l,h]    = sum_{j=1..2046} w[h,|l-j|]               (l in 1..2046, else 0)
// B=4, S=2048, H=12, D=64. Outputs fp32: pbv (6291456) then z_pb (24576).
//
// TWO dispatches:
//  1) prep_kernel (24 blocks x 256): blocks 0..11 build the global A-fragment table
//     g_wt[h][8q+i] = bf16(w_ext[2174-q-i]) (every 16B slot q IS a ready MFMA A-frag,
//     835 KB, L2-resident); blocks 12..23 compute z_pb.
//  2) gemm_kernel (3072 blocks x 64 = ONE WAVE per block): NO LDS, NO barriers, no
//     per-block table build. TLP attack: 6 rounds showed hipcc will not sustain a
//     register pipeline (sinks loads / remats window ds_reads; MfmaUtil pinned ~15% at
//     1.5-3 waves/SIMD). So: acc 32 + transient A-frags only -> VGPR ~120 ->
//     __launch_bounds__(64,4) = 16 waves/CU, latency hidden by TLP instead of ILP.
//     Per iter per wave: 10 A dwordx4 (distinct imm offsets off one moving base, L1/L2
//     hot, re-read fresh each iter - nothing for the allocator to collapse) + 16 B scalar
//     dwords (v fp32 direct, dist-1, cvt in-reg) + 16 MFMA under setprio.

typedef short short8 __attribute__((ext_vector_type(8)));   // 8 x bf16 bits (4 VGPRs)
typedef float floatx4 __attribute__((ext_vector_type(4)));  // MFMA accumulator

#define QN 4352   // A-table fragment slots per h; q range used = [127, 4214]

__device__ __attribute__((aligned(16))) short g_wt[12 * QN * 8];   // 835 KB

__device__ __forceinline__ unsigned short f2bf(float f) {
  union { __hip_bfloat16 b; unsigned short u; } cv;
  cv.b = __float2bfloat16(f);  // RNE
  return cv.u;
}

// ---------------- dispatch 1: g_wt build + z_pb ----------------
__global__ __launch_bounds__(256) void prep_kernel(const float* __restrict__ w,
                                                   float* __restrict__ out) {
  __shared__ float zls[4096];
  __shared__ float wsum[4];

  const int bx  = blockIdx.x;
  const int tid = threadIdx.x;

  if (bx < 12) {   // ---- A fragment table for h = bx ----
    const int h = bx;
    const float* wh = w + (size_t)h * 2048;
    short* F = g_wt + (size_t)h * QN * 8;
    for (int q = tid; q < QN; q += 256) {
      unsigned short buf[8] __attribute__((aligned(16)));
      #pragma unroll
      for (int i = 0; i < 8; ++i) {
        int t = 2174 - q - i;
        int a = t < 0 ? -t : t;
        buf[i] = (a <= 2045) ? f2bf(wh[a]) : (unsigned short)0;
      }
      *(short8*)&F[(size_t)q * 8] = *(const short8*)buf;
    }
    return;
  }

  // ---- zpb: z[i+1] = P[i] + P[2045-i] - w[h,0] ----
  const int h = bx - 12;
  float* wvv = zls;          // [2048]
  float* pfx = zls + 2048;   // [2048]
  const float* wh = w + (size_t)h * 2048;
  float* zout = out + 6291456;
  for (int i = tid; i < 2048; i += 256) wvv[i] = (i < 2046) ? wh[i] : 0.f;
  __syncthreads();
  const int base = tid * 8;
  float run0 = 0.f;
  #pragma unroll
  for (int k = 0; k < 8; ++k) run0 += wvv[base + k];
  float x = run0;
  #pragma unroll
  for (int dd = 1; dd < 64; dd <<= 1) {
    float y = __shfl_up(x, dd);
    if ((tid & 63) >= dd) x += y;
  }
  if ((tid & 63) == 63) wsum[tid >> 6] = x;
  __syncthreads();
  const int wid4 = tid >> 6;
  float woff = 0.f;
  #pragma unroll
  for (int u = 0; u < 3; ++u) { float t = wsum[u]; if (u < wid4) woff += t; }
  float pr = x + woff - run0;
  #pragma unroll
  for (int k = 0; k < 8; ++k) { pr += wvv[base + k]; pfx[base + k] = pr; }
  __syncthreads();
  for (int i = tid; i < 2046; i += 256) {
    float z = pfx[i] + pfx[2045 - i] - wvv[0];
    zout[(size_t)(i + 1) * 12 + h] = z;
  }
  if (tid == 0) { zout[h] = 0.f; zout[(size_t)2047 * 12 + h] = 0.f; }
}

// ---------------- dispatch 2: Toeplitz GEMM, 128j x 16nd per WAVE, no LDS --------------
__global__ __launch_bounds__(64, 4) void gemm_kernel(const float* __restrict__ v,
                                                     float* __restrict__ out) {
  const int bx   = blockIdx.x;
  const int lane = threadIdx.x;        // one wave per block

  // bx = jt*192 + slice: same-(n,h) blocks are 192 apart (192%8==0) -> same XCD ->
  // v-slice + A-window L2-resident across the 16 j-tiles that re-read them.
  const int slice = bx % 192;
  const int jt    = bx / 192;          // 16 j-tiles
  const int ndq   = slice & 3;         // d-quarter
  const int sl    = slice >> 2;        // (h, n)
  const int n = sl & 3;
  const int h = sl >> 2;
  const int lm = lane & 15, quad = lane >> 4;
  const int jb = jt * 128;
  const int d  = ndq * 16 + lm;        // wave owns a 16-d strip

  // B source: v[n][l][h][d], l-stride 768 floats. Per instr: 4 quads x 16 consecutive d
  // = 4 fully-used 64B segments.
  const float* vrow = v + (((size_t)n * 2048) * 12 + h) * 64 + d;

  // A: fragment q = t*64 + 16*g + qbase, g = 2*kc - ma in [-7,2] -> 10 distinct
  // imm offsets (-1792..+512 B) off one per-iter base. F[8q+i] = w_ext[127+jb-p0-i]
  // with q = p0 + 2047-jb (q in [127,4214] for all lanes/tiles: in-bounds).
  const int qbase = 127 + quad * 8 - lm + 2047 - jb;
  const short* wtb = g_wt + (size_t)h * QN * 8 + (size_t)qbase * 8;

  // bare pack (compiler pairs to v_cvt_pk_bf16_f32)
  auto packB = [&](const float* f, short8& b0, short8& b1) {
    #pragma unroll
    for (int i = 0; i < 8; ++i) {
      b0[i] = (short)f2bf(f[i]);
      b1[i] = (short)f2bf(f[8 + i]);
    }
  };

  // B for t=0
  float r0[16];
  {
    const int lb = quad * 8;
    #pragma unroll
    for (int i = 0; i < 8; ++i) r0[i]     = vrow[(size_t)(lb + i) * 768];
    #pragma unroll
    for (int i = 0; i < 8; ++i) r0[8 + i] = vrow[(size_t)(lb + 32 + i) * 768];
  }
  short8 bc0, bc1;
  packB(r0, bc0, bc1);
  if (quad == 0) bc0[0] = 0;           // l = 0 border (t=0, quad0, elem0)

  floatx4 acc[8];
  #pragma unroll
  for (int ma = 0; ma < 8; ++ma) acc[ma] = (floatx4){0.f, 0.f, 0.f, 0.f};

  #pragma unroll 4
  for (int t = 0; t < 32; ++t) {
    // A-frags for THIS iter, re-read fresh (L1/L2-hot; no live window to collapse)
    const short* wp = wtb + (size_t)t * 512;   // t*64 slots * 8 shorts
    short8 af[10];
    #pragma unroll
    for (int gi = 0; gi < 10; ++gi)
      af[gi] = *(const short8*)&wp[(gi - 7) * 128];   // 16-slot (256 B) spacing

    // B loads for t+1 (dist-1; exposure covered by 4 waves/SIMD TLP)
    float rN[16];
    if (t < 31) {
      const int lb2 = (t + 1) * 64 + quad * 8;
      #pragma unroll
      for (int i = 0; i < 8; ++i) rN[i]     = vrow[(size_t)(lb2 + i) * 768];
      #pragma unroll
      for (int i = 0; i < 8; ++i) rN[8 + i] = vrow[(size_t)(lb2 + 32 + i) * 768];
    }

    __builtin_amdgcn_s_setprio(1);
    #pragma unroll
    for (int ma = 0; ma < 8; ++ma)   // kc=0: g = -ma  -> idx 7-ma
      acc[ma] = __builtin_amdgcn_mfma_f32_16x16x32_bf16(af[7 - ma], bc0, acc[ma], 0, 0, 0);
    #pragma unroll
    for (int ma = 0; ma < 8; ++ma)   // kc=1: g = 2-ma -> idx 9-ma
      acc[ma] = __builtin_amdgcn_mfma_f32_16x16x32_bf16(af[9 - ma], bc1, acc[ma], 0, 0, 0);
    __builtin_amdgcn_s_setprio(0);

    if (t < 31) {
      short8 nb0, nb1;
      packB(rN, nb0, nb1);
      if (t == 30 && quad == 3) nb1[7] = 0;   // l = 2047 border (t=31, bc1, quad3, elem7)
      bc0 = nb0; bc1 = nb1;
    }
  }

  // epilogue: D row = quad*4 + r (j), col = lm (d); zero rows j=0 and j=2047
  float* obase = out + (size_t)n * 1572864 + (size_t)h * 64 + d;
  #pragma unroll
  for (int ma = 0; ma < 8; ++ma) {
    floatx4 cc = acc[ma];
    #pragma unroll
    for (int r = 0; r < 4; ++r) {
      int j = jb + ma * 16 + quad * 4 + r;
      float val = (j == 0 || j == 2047) ? 0.f : cc[r];
      obase[(size_t)j * 768] = val;
    }
  }
}

extern "C" void kernel_launch(void* const* d_in, const int* in_sizes, int n_in,
                              void* d_out, int out_size, void* d_ws, size_t ws_size,
                              hipStream_t stream) {
  const float* v = (const float*)d_in[0];   // (4,2048,12,64) fp32
  const float* w = (const float*)d_in[1];   // (12,2048) fp32
  float* out = (float*)d_out;               // pbv (6291456) + z_pb (24576) fp32
  prep_kernel<<<dim3(24), 256, 0, stream>>>(w, out);
  gemm_kernel<<<dim3(3072), 64, 0, stream>>>(v, out);
}

// Round 8
// 122.204 us; speedup vs baseline: 1.2307x; 1.2307x over previous
//
#include <hip/hip_runtime.h>
#include <hip/hip_bf16.h>

// PositionalBias: pbv[n,j,h,d] = sum_{l=1..2046} w[h,|j-l|] * v[n,l,h,d]  (j in 1..2046, else 0)
//                 z_pb[l,h]    = sum_{j=1..2046} w[h,|l-j|]               (l in 1..2046, else 0)
// B=4, S=2048, H=12, D=64. Outputs fp32: pbv (6291456) then z_pb (24576).
//
// SINGLE-DISPATCH fused kernel (780 blocks x 256): 0..767 Toeplitz GEMM, 768..779 z_pb.
// GEMM block = 128j x 64nd, 4 waves x 16-d strips.
//  - A: per-block 8x-shifted reversed-Toeplitz bf16 table in LDS (built once), aligned
//    ds_read_b128 sliding 10-frag diagonal window (compiler-scheduled lgkm domain).
//  - B: *** inline-asm buffer_load pipeline *** - the fix for the disease seen in rounds
//    0-7 (hipcc sinks/serializes B loads; VGPR collapsed to 56-120, MfmaUtil pinned at
//    12-16%). 16 buffer_load_dword per iter via SRSRC (base = block's (n,h) v-slice,
//    wave-uniform; 16 precomputed per-lane voffsets; t-dependence = soffset SGPR ->
//    ZERO per-iter address VALU). Distance-2 double buffer rb[2][16], parity-static.
//    s_waitcnt vmcnt(16) + sched_barrier(0) before each pack (asm volatile loads cannot
//    be sunk; counted wait keeps 16-32 loads in flight across the MFMA clusters).
//  - 16 MFMA 16x16x32 per iter under setprio; full unroll -> all guards compile-time.

typedef short short8 __attribute__((ext_vector_type(8)));   // 8 x bf16 bits (4 VGPRs)
typedef float floatx4 __attribute__((ext_vector_type(4)));  // MFMA accumulator
typedef unsigned uint4v __attribute__((ext_vector_type(4)));

#define TL 2280   // A-table length per shifted copy (shorts); 8 copies = 36.5 KB LDS

__device__ __forceinline__ unsigned short f2bf(float f) {
  union { __hip_bfloat16 b; unsigned short u; } cv;
  cv.b = __float2bfloat16(f);  // RNE
  return cv.u;
}

__global__ __launch_bounds__(256, 3) void fused_kernel(const float* __restrict__ v,
                                                       const float* __restrict__ w,
                                                       float* __restrict__ out) {
  __shared__ __attribute__((aligned(16))) short Tls[8 * TL];  // 36.5 KB (aliased by zpb)

  const int bx  = blockIdx.x;
  const int tid = threadIdx.x;

  if (bx >= 768) {   // ---------------- zpb: z[i+1] = P[i] + P[2045-i] - w[h,0] -------------
    const int h = bx - 768;
    float* wv  = (float*)Tls;          // [2048]
    float* pfx = ((float*)Tls) + 2048; // [2048]
    __shared__ float wsum[4];
    const float* wh = w + (size_t)h * 2048;
    float* zout = out + 6291456;
    for (int i = tid; i < 2048; i += 256) wv[i] = (i < 2046) ? wh[i] : 0.f;
    __syncthreads();
    const int base = tid * 8;
    float run0 = 0.f;
    #pragma unroll
    for (int k = 0; k < 8; ++k) run0 += wv[base + k];
    float x = run0;
    #pragma unroll
    for (int dd = 1; dd < 64; dd <<= 1) {
      float y = __shfl_up(x, dd);
      if ((tid & 63) >= dd) x += y;
    }
    if ((tid & 63) == 63) wsum[tid >> 6] = x;
    __syncthreads();
    const int wid4 = tid >> 6;
    float woff = 0.f;
    #pragma unroll
    for (int u = 0; u < 3; ++u) { float t = wsum[u]; if (u < wid4) woff += t; }
    float pr = x + woff - run0;
    #pragma unroll
    for (int k = 0; k < 8; ++k) { pr += wv[base + k]; pfx[base + k] = pr; }
    __syncthreads();
    for (int i = tid; i < 2046; i += 256) {
      float z = pfx[i] + pfx[2045 - i] - wv[0];
      zout[(size_t)(i + 1) * 12 + h] = z;
    }
    if (tid == 0) { zout[h] = 0.f; zout[(size_t)2047 * 12 + h] = 0.f; }
    return;
  }

  // ---------------- GEMM block ----------------
  // Same-slice blocks are 48 apart (48%8==0) -> same XCD -> v-slice L2-resident.
  const int slice = bx % 48;          // (h, ndt)
  const int jt    = bx / 48;          // 16 j-tiles
  const int ndt = slice & 3;
  const int h   = slice >> 2;
  const int lane = tid & 63, wid = tid >> 6;
  const int lm = lane & 15, quad = lane >> 4;
  const int jb = jt * 128;
  const int d  = wid * 16 + lm;       // lane's head-dim index

  // ---- B: SRSRC buffer descriptor over the block's (n,h) v-slice ----
  // byte addr of v[ndt][l][h][d] = base + d*4 + l*3072; l = t*64 + (quad*8 + k),
  // k in {0..7, 32..39}. voff[i] = per-lane static part (16 VGPRs, computed once);
  // soffset = (t)*196608 (wave-uniform SGPR). Zero per-iter address VALU.
  const float* vbase = v + (((size_t)ndt * 2048) * 12 + h) * 64;
  uint4v rsrc;
  {
    unsigned long long pa = (unsigned long long)(const void*)vbase;
    rsrc[0] = (unsigned)pa;
    rsrc[1] = (unsigned)(pa >> 32);   // stride 0
    rsrc[2] = 0xFFFFFFFFu;            // num_records: bounds check disabled
    rsrc[3] = 0x00020000u;            // raw dword buffer
  }
  unsigned voff[16];
  #pragma unroll
  for (int i = 0; i < 8; ++i) {
    voff[i]     = (unsigned)(d * 4 + (quad * 8 + i) * 3072);
    voff[8 + i] = (unsigned)(d * 4 + (quad * 8 + 32 + i) * 3072);
  }

  float rb[2][16];   // distance-2 double buffer (parity-static indexing)
  // prologue: issue t=0 and t=1 loads (in FIFO order), latency hides under table build
  #pragma unroll
  for (int i = 0; i < 16; ++i)
    asm volatile("buffer_load_dword %0, %1, %2, %3 offen"
                 : "=v"(rb[0][i]) : "v"(voff[i]), "s"(rsrc), "s"(0));
  #pragma unroll
  for (int i = 0; i < 16; ++i)
    asm volatile("buffer_load_dword %0, %1, %2, %3 offen"
                 : "=v"(rb[1][i]) : "v"(voff[i]), "s"(rsrc), "s"(196608));

  // build reversed, 8x-shifted Toeplitz table: T_c[p] = w_ext[127 + jb - p - c]
  const float* wh = w + (size_t)h * 2048;
  for (int g = tid; g < 8 * (TL / 8); g += 256) {
    int c  = g / (TL / 8);
    int p8 = (g - c * (TL / 8)) * 8;
    unsigned short buf[8] __attribute__((aligned(16)));
    #pragma unroll
    for (int i = 0; i < 8; ++i) {
      int t = 127 + jb - (p8 + i) - c;
      int a = t < 0 ? -t : t;
      buf[i] = (a <= 2045) ? f2bf(wh[a]) : (unsigned short)0;
    }
    *(short8*)&Tls[c * TL + p8] = *(const short8*)buf;
  }
  __syncthreads();   // drains vmcnt too: t=0/1 data resident at loop entry

  // A-frag at slot p+abase: value_i = w_ext[j - k]; aligned b128 via copy (p0 & 7).
  const int abase = 127 + quad * 8 - lm;
  auto load_af = [&](int p) -> short8 {
    int p0 = p + abase;
    int c = p0 & 7;
    return *(const short8*)&Tls[c * TL + (p0 - c)];
  };

  short8 afr[10];                      // afr[i] = diagonal g = i-7 relative to current l0
  #pragma unroll
  for (int i = 0; i < 10; ++i) afr[i] = load_af((i - 7) * 16);

  floatx4 acc[8];
  #pragma unroll
  for (int ma = 0; ma < 8; ++ma) acc[ma] = (floatx4){0.f, 0.f, 0.f, 0.f};

  #pragma unroll                        // FULL unroll: parity/guards compile-time
  for (int t = 0; t < 32; ++t) {
    // wait for iter-t's 16 loads (t+1's 16 may stay in flight); pin with sched_barrier
    if (t == 31) { asm volatile("s_waitcnt vmcnt(0)" ::: "memory"); }
    else         { asm volatile("s_waitcnt vmcnt(16)" ::: "memory"); }
    __builtin_amdgcn_sched_barrier(0);

    // pack t's raw fp32 -> bf16 B-frags (compiler pairs to v_cvt_pk_bf16_f32)
    short8 b0, b1;
    #pragma unroll
    for (int i = 0; i < 8; ++i) {
      b0[i] = (short)f2bf(rb[t & 1][i]);
      b1[i] = (short)f2bf(rb[t & 1][8 + i]);
    }
    if (t == 0  && quad == 0) b0[0] = 0;   // l = 0 border
    if (t == 31 && quad == 3) b1[7] = 0;   // l = 2047 border

    // issue loads for t+2 into the buffer just consumed (asm volatile: cannot be sunk)
    if (t < 30) {
      const int so = (t + 2) * 196608;
      #pragma unroll
      for (int i = 0; i < 16; ++i)
        asm volatile("buffer_load_dword %0, %1, %2, %3 offen"
                     : "=v"(rb[t & 1][i]) : "v"(voff[i]), "s"(rsrc), "s"(so));
    }

    // A prefetch distance 1: next iter's fresh diagonals g = -1,0,1,2
    short8 na0, na1, na2, na3;
    if (t < 31) {
      const int l0n = t * 64 + 64;
      na0 = load_af(l0n - 16);
      na1 = load_af(l0n);
      na2 = load_af(l0n + 16);
      na3 = load_af(l0n + 32);
    }

    __builtin_amdgcn_s_setprio(1);
    #pragma unroll
    for (int ma = 0; ma < 8; ++ma)   // kc=0: g = -ma  -> idx 7-ma
      acc[ma] = __builtin_amdgcn_mfma_f32_16x16x32_bf16(afr[7 - ma], b0, acc[ma], 0, 0, 0);
    #pragma unroll
    for (int ma = 0; ma < 8; ++ma)   // kc=1: g = 2-ma -> idx 9-ma
      acc[ma] = __builtin_amdgcn_mfma_f32_16x16x32_bf16(afr[9 - ma], b1, acc[ma], 0, 0, 0);
    __builtin_amdgcn_s_setprio(0);

    if (t < 31) {
      #pragma unroll
      for (int i = 0; i < 6; ++i) afr[i] = afr[i + 4];
      afr[6] = na0; afr[7] = na1; afr[8] = na2; afr[9] = na3;
    }
  }

  // epilogue: D row = quad*4 + r (j), col = lm (d); zero rows j=0 and j=2047
  float* obase = out + (size_t)ndt * 1572864 + (size_t)h * 64 + d;
  #pragma unroll
  for (int ma = 0; ma < 8; ++ma) {
    floatx4 cc = acc[ma];
    #pragma unroll
    for (int r = 0; r < 4; ++r) {
      int j = jb + ma * 16 + quad * 4 + r;
      float val = (j == 0 || j == 2047) ? 0.f : cc[r];
      obase[(size_t)j * 768] = val;
    }
  }
}

extern "C" void kernel_launch(void* const* d_in, const int* in_sizes, int n_in,
                              void* d_out, int out_size, void* d_ws, size_t ws_size,
                              hipStream_t stream) {
  const float* v = (const float*)d_in[0];   // (4,2048,12,64) fp32
  const float* w = (const float*)d_in[1];   // (12,2048) fp32
  float* out = (float*)d_out;               // pbv (6291456) + z_pb (24576) fp32
  fused_kernel<<<dim3(780), 256, 0, stream>>>(v, w, out);
}

// Round 9
// 109.912 us; speedup vs baseline: 1.3684x; 1.1118x over previous
//
#include <hip/hip_runtime.h>
#include <hip/hip_bf16.h>

// PositionalBias: pbv[n,j,h,d] = sum_{l=1..2046} w[h,|j-l|] * v[n,l,h,d]  (j in 1..2046, else 0)
//                 z_pb[l,h]    = sum_{j=1..2046} w[h,|l-j|]               (l in 1..2046, else 0)
// B=4, S=2048, H=12, D=64. Outputs fp32: pbv (6291456) then z_pb (24576).
//
// TWO dispatches (R4 structure, g_wt build parallelized 12 -> 192 blocks):
//  1) prep_kernel (972 blocks):
//     0..767  : LDS-transpose+convert v -> g_vt[n][h][d][l] bf16 (128-l x 64-d tile per
//               block; padded-stride LDS transpose -> coalesced reads AND writes),
//               borders l=0/2047 zeroed
//     768..779: z_pb
//     780..971: A fragment table g_wt: F[h][8q+i] = bf16(w_ext[2174 - q - i]);
//               192 blocks = 12 h x 16 chunks of 272 slots (was 12 blocks = 25us tail).
//  2) gemm_kernel (768 blocks, 4 blocks/CU): per block, copy its 2304-slot A-window from
//     g_wt into LDS (coalesced), then per iter per wave: 4 ds_read_b128 (A) +
//     2 global dwordx4 (B bf16, distance-2) + 16 MFMA under setprio.

typedef short short8 __attribute__((ext_vector_type(8)));   // 8 x bf16 bits (4 VGPRs)
typedef float floatx4 __attribute__((ext_vector_type(4)));  // MFMA accumulator
typedef unsigned uint4_ __attribute__((ext_vector_type(4)));

#define QN 4352   // A-table fragment slots per h; max read = (2047-0)+2303 = 4350

__device__ __attribute__((aligned(16))) short g_vt[4 * 12 * 64 * 2048];  // 12.6 MB
__device__ __attribute__((aligned(16))) short g_wt[12 * QN * 8];         // 835 KB

__device__ __forceinline__ unsigned short f2bf(float f) {
  union { __hip_bfloat16 b; unsigned short u; } cv;
  cv.b = __float2bfloat16(f);  // RNE
  return cv.u;
}

// ---------------- dispatch 1: v -> g_vt (LDS transpose), z_pb, w -> g_wt ----------------
__global__ __launch_bounds__(256) void prep_kernel(const float* __restrict__ v,
                                                   const float* __restrict__ w,
                                                   float* __restrict__ out) {
  __shared__ unsigned tls[64 * 65];   // transpose tile: [d][l-pair], pad->2-way only
  __shared__ float zls[4096];
  __shared__ float wsum[4];

  const int bx  = blockIdx.x;
  const int tid = threadIdx.x;

  if (bx >= 780) {   // ---- A fragment table, 192 blocks: (h, 272-slot chunk) ----
    const int idx = bx - 780;
    const int h = idx >> 4;
    const int c = idx & 15;
    const float* wh = w + (size_t)h * 2048;
    short* F = g_wt + (size_t)h * QN * 8;
    const int qs = c * 272;
    for (int q = qs + tid; q < qs + 272; q += 256) {
      unsigned short buf[8] __attribute__((aligned(16)));
      #pragma unroll
      for (int i = 0; i < 8; ++i) {
        int t = 2174 - q - i;
        int a = t < 0 ? -t : t;
        buf[i] = (a <= 2045) ? f2bf(wh[a]) : (unsigned short)0;
      }
      *(short8*)&F[(size_t)q * 8] = *(const short8*)buf;
    }
    return;
  }

  if (bx >= 768) {   // ---- zpb: z[i+1] = P[i] + P[2045-i] - w[h,0] ----
    const int h = bx - 768;
    float* wvv = zls;          // [2048]
    float* pfx = zls + 2048;   // [2048]
    const float* wh = w + (size_t)h * 2048;
    float* zout = out + 6291456;
    for (int i = tid; i < 2048; i += 256) wvv[i] = (i < 2046) ? wh[i] : 0.f;
    __syncthreads();
    const int base = tid * 8;
    float run0 = 0.f;
    #pragma unroll
    for (int k = 0; k < 8; ++k) run0 += wvv[base + k];
    float x = run0;
    #pragma unroll
    for (int dd = 1; dd < 64; dd <<= 1) {
      float y = __shfl_up(x, dd);
      if ((tid & 63) >= dd) x += y;
    }
    if ((tid & 63) == 63) wsum[tid >> 6] = x;
    __syncthreads();
    const int wid4 = tid >> 6;
    float woff = 0.f;
    #pragma unroll
    for (int u = 0; u < 3; ++u) { float t = wsum[u]; if (u < wid4) woff += t; }
    float pr = x + woff - run0;
    #pragma unroll
    for (int k = 0; k < 8; ++k) { pr += wvv[base + k]; pfx[base + k] = pr; }
    __syncthreads();
    for (int i = tid; i < 2046; i += 256) {
      float z = pfx[i] + pfx[2045 - i] - wvv[0];
      zout[(size_t)(i + 1) * 12 + h] = z;
    }
    if (tid == 0) { zout[h] = 0.f; zout[(size_t)2047 * 12 + h] = 0.f; }
    return;
  }

  // ---- transpose: block = (n, h, 128-l chunk). Wave reads 32 l x 64 d (coalesced),
  //      LDS-transposes, then threads store full 64B lines per d-row. ----
  const int chunk = bx & 15;            // 16 chunks of 128 l
  const int slice = bx >> 4;            // 0..47
  const int n = slice / 12, h = slice - n * 12;
  const int lane = tid & 63;            // d on read side
  const int wv   = tid >> 6;            // 0..3
  const int lbase = chunk * 128 + wv * 32;

  const float* src = v + (((size_t)n * 2048 + lbase) * 12 + h) * 64 + lane;
  #pragma unroll
  for (int kk = 0; kk < 16; ++kk) {
    float f0 = src[(size_t)(2 * kk)     * 768];
    float f1 = src[(size_t)(2 * kk + 1) * 768];
    int l = lbase + 2 * kk;
    unsigned lo = (l == 0)        ? 0u : (unsigned)f2bf(f0);
    unsigned hi = (l + 1 == 2047) ? 0u : (unsigned)f2bf(f1);
    tls[lane * 65 + wv * 16 + kk] = lo | (hi << 16);
  }
  __syncthreads();

  const int r = tid >> 2;               // d-row on store side
  const int m = tid & 3;                // 64B segment within row
  unsigned xbuf[16];
  #pragma unroll
  for (int k = 0; k < 16; ++k) xbuf[k] = tls[r * 65 + m * 16 + k];
  unsigned* dstu = (unsigned*)(g_vt + (((size_t)n * 12 + h) * 64 + r) * 2048 +
                               (size_t)chunk * 128) + m * 16;
  #pragma unroll
  for (int k4 = 0; k4 < 4; ++k4) {
    uint4_ val = {xbuf[k4 * 4], xbuf[k4 * 4 + 1], xbuf[k4 * 4 + 2], xbuf[k4 * 4 + 3]};
    *(uint4_*)&dstu[k4 * 4] = val;
  }
}

// ---------------- dispatch 2: Toeplitz GEMM, 128j x 64nd per block, 4 blocks/CU ----------
__global__ __launch_bounds__(256, 4) void gemm_kernel(float* __restrict__ out) {
  __shared__ __attribute__((aligned(16))) short Als[2304 * 8];  // 36,864 B

  const int bx  = blockIdx.x;
  const int tid = threadIdx.x;

  // Same-slice blocks are 48 apart (48%8==0) -> same XCD -> vt-slice + A-window L2-resident.
  const int slice = bx % 48;          // (h, ndt)
  const int jt    = bx / 48;          // 16 j-tiles
  const int ndt = slice & 3;
  const int h   = slice >> 2;
  const int lane = tid & 63;
  const int wid  = tid >> 6;
  const int lm = lane & 15, quad = lane >> 4;
  const int jb = jt * 128;
  const int d  = wid * 16 + lm;       // wave owns a 16-d strip

  // B: bf16 v^T row (borders pre-zeroed). One dwordx4 IS the B-fragment.
  const short* vtb = g_vt + (((size_t)ndt * 12 + h) * 64 + d) * 2048;
  auto load_bf = [&](int lb) -> short8 {
    return *(const short8*)&vtb[lb];
  };

  // issue t=0,1 B-frags first: latency hides under the A-window copy
  short8 bc0 = load_bf(quad * 8);
  short8 bc1 = load_bf(32 + quad * 8);
  short8 bn0 = load_bf(64 + quad * 8);
  short8 bn1 = load_bf(96 + quad * 8);

  // copy this block's A-window g_wt[h][qbase .. qbase+2303] -> LDS (coalesced, no VALU)
  const short* wsrc = g_wt + (size_t)h * QN * 8 + (size_t)(2047 - jb) * 8;
  #pragma unroll
  for (int k = 0; k < 9; ++k) {
    *(short8*)&Als[(size_t)(k * 256 + tid) * 8] =
        *(const short8*)&wsrc[(size_t)(k * 256 + tid) * 8];
  }
  __syncthreads();   // the only block-wide sync

  // A-frag at slot p+abase (16B each): value_i = w_ext[j - k] for this lane's (quad,lm).
  // p = l0 + 16*g, abase = 127 + quad*8 - lm.
  const int abase = 127 + quad * 8 - lm;
  auto load_af = [&](int p) -> short8 {
    return *(const short8*)&Als[(size_t)(p + abase) * 8];
  };

  short8 afr[10];                      // afr[i] = diagonal g = i-7 relative to current l0
  #pragma unroll
  for (int i = 0; i < 10; ++i) afr[i] = load_af((i - 7) * 16);

  floatx4 acc[8];
  #pragma unroll
  for (int ma = 0; ma < 8; ++ma) acc[ma] = (floatx4){0.f, 0.f, 0.f, 0.f};

  #pragma unroll 4
  for (int t = 0; t < 32; ++t) {
    const int l0 = t * 64;
    // B prefetch distance 2 (branchless clamp; tail re-reads t=31: harmless)
    int t2 = t + 2; if (t2 > 31) t2 = 31;
    const int lb = t2 * 64 + quad * 8;
    short8 bm0 = load_bf(lb);
    short8 bm1 = load_bf(lb + 32);
    // A prefetch distance 1: next iter's fresh diagonals g = -1,0,1,2
    const int l0n = (t < 31) ? l0 + 64 : l0;
    short8 na0 = load_af(l0n - 16);
    short8 na1 = load_af(l0n);
    short8 na2 = load_af(l0n + 16);
    short8 na3 = load_af(l0n + 32);

    __builtin_amdgcn_s_setprio(1);
    #pragma unroll
    for (int ma = 0; ma < 8; ++ma)   // kc=0: g = -ma  -> idx 7-ma
      acc[ma] = __builtin_amdgcn_mfma_f32_16x16x32_bf16(afr[7 - ma], bc0, acc[ma], 0, 0, 0);
    #pragma unroll
    for (int ma = 0; ma < 8; ++ma)   // kc=1: g = 2-ma -> idx 9-ma
      acc[ma] = __builtin_amdgcn_mfma_f32_16x16x32_bf16(afr[9 - ma], bc1, acc[ma], 0, 0, 0);
    __builtin_amdgcn_s_setprio(0);

    // rotate pipelines
    #pragma unroll
    for (int i = 0; i < 6; ++i) afr[i] = afr[i + 4];
    afr[6] = na0; afr[7] = na1; afr[8] = na2; afr[9] = na3;
    bc0 = bn0; bc1 = bn1;
    bn0 = bm0; bn1 = bm1;
  }

  // epilogue: D row = quad*4 + r (j), col = lm (d); zero rows j=0 and j=2047
  float* obase = out + (size_t)ndt * 1572864 + (size_t)h * 64 + d;
  #pragma unroll
  for (int ma = 0; ma < 8; ++ma) {
    floatx4 cc = acc[ma];
    #pragma unroll
    for (int r = 0; r < 4; ++r) {
      int j = jb + ma * 16 + quad * 4 + r;
      float val = (j == 0 || j == 2047) ? 0.f : cc[r];
      obase[(size_t)j * 768] = val;
    }
  }
}

extern "C" void kernel_launch(void* const* d_in, const int* in_sizes, int n_in,
                              void* d_out, int out_size, void* d_ws, size_t ws_size,
                              hipStream_t stream) {
  const float* v = (const float*)d_in[0];   // (4,2048,12,64) fp32
  const float* w = (const float*)d_in[1];   // (12,2048) fp32
  float* out = (float*)d_out;               // pbv (6291456) + z_pb (24576) fp32
  prep_kernel<<<dim3(972), 256, 0, stream>>>(v, w, out);
  gemm_kernel<<<dim3(768), 256, 0, stream>>>(out);
}

// Round 10
// 107.973 us; speedup vs baseline: 1.3929x; 1.0180x over previous
//
#include <hip/hip_runtime.h>
#include <hip/hip_bf16.h>

// PositionalBias: pbv[n,j,h,d] = sum_{l=1..2046} w[h,|j-l|] * v[n,l,h,d]  (j in 1..2046, else 0)
//                 z_pb[l,h]    = sum_{j=1..2046} w[h,|l-j|]               (l in 1..2046, else 0)
// B=4, S=2048, H=12, D=64. Outputs fp32: pbv (6291456) then z_pb (24576).
//
// TWO dispatches (R9 structure; gemm inner loop converted to asm-pinned pipeline):
//  1) prep_kernel (972 blocks): 0..767 LDS-transpose v -> g_vt[n][h][d][l] bf16 (borders
//     zeroed); 768..779 z_pb; 780..971 A-fragment table g_wt (12 h x 16 chunks).
//  2) gemm_kernel (768 blocks): A-window LDS copy once, then per iter per wave:
//     4 asm ds_read_b128 (A, t+1) + 2 asm global_load_dwordx4 (B bf16, t+2) issued at top,
//     s_waitcnt vmcnt(4) (counted, never 0 mid-loop) + sched_barrier before 16 MFMA,
//     s_waitcnt lgkmcnt(0) + sched_barrier before window rotation. asm volatile results
//     CANNOT be rematerialized or sunk -> the afr[10] register window finally stays live
//     (9 rounds of evidence: hipcc otherwise collapses it to ~12 LDS reads/iter, making
//     LDS throughput the hidden bottleneck at MfmaUtil~15%).

typedef short short8 __attribute__((ext_vector_type(8)));   // 8 x bf16 bits (4 VGPRs)
typedef float floatx4 __attribute__((ext_vector_type(4)));  // MFMA accumulator
typedef unsigned uint4_ __attribute__((ext_vector_type(4)));

#define QN 4352   // A-table fragment slots per h; max read = (2047-0)+2303 = 4350

__device__ __attribute__((aligned(16))) short g_vt[4 * 12 * 64 * 2048];  // 12.6 MB
__device__ __attribute__((aligned(16))) short g_wt[12 * QN * 8];         // 835 KB

__device__ __forceinline__ unsigned short f2bf(float f) {
  union { __hip_bfloat16 b; unsigned short u; } cv;
  cv.b = __float2bfloat16(f);  // RNE
  return cv.u;
}

// ---------------- dispatch 1: v -> g_vt (LDS transpose), z_pb, w -> g_wt ----------------
__global__ __launch_bounds__(256) void prep_kernel(const float* __restrict__ v,
                                                   const float* __restrict__ w,
                                                   float* __restrict__ out) {
  __shared__ unsigned tls[64 * 65];   // transpose tile: [d][l-pair], pad->2-way only
  __shared__ float zls[4096];
  __shared__ float wsum[4];

  const int bx  = blockIdx.x;
  const int tid = threadIdx.x;

  if (bx >= 780) {   // ---- A fragment table, 192 blocks: (h, 272-slot chunk) ----
    const int idx = bx - 780;
    const int h = idx >> 4;
    const int c = idx & 15;
    const float* wh = w + (size_t)h * 2048;
    short* F = g_wt + (size_t)h * QN * 8;
    const int qs = c * 272;
    for (int q = qs + tid; q < qs + 272; q += 256) {
      unsigned short buf[8] __attribute__((aligned(16)));
      #pragma unroll
      for (int i = 0; i < 8; ++i) {
        int t = 2174 - q - i;
        int a = t < 0 ? -t : t;
        buf[i] = (a <= 2045) ? f2bf(wh[a]) : (unsigned short)0;
      }
      *(short8*)&F[(size_t)q * 8] = *(const short8*)buf;
    }
    return;
  }

  if (bx >= 768) {   // ---- zpb: z[i+1] = P[i] + P[2045-i] - w[h,0] ----
    const int h = bx - 768;
    float* wvv = zls;          // [2048]
    float* pfx = zls + 2048;   // [2048]
    const float* wh = w + (size_t)h * 2048;
    float* zout = out + 6291456;
    for (int i = tid; i < 2048; i += 256) wvv[i] = (i < 2046) ? wh[i] : 0.f;
    __syncthreads();
    const int base = tid * 8;
    float run0 = 0.f;
    #pragma unroll
    for (int k = 0; k < 8; ++k) run0 += wvv[base + k];
    float x = run0;
    #pragma unroll
    for (int dd = 1; dd < 64; dd <<= 1) {
      float y = __shfl_up(x, dd);
      if ((tid & 63) >= dd) x += y;
    }
    if ((tid & 63) == 63) wsum[tid >> 6] = x;
    __syncthreads();
    const int wid4 = tid >> 6;
    float woff = 0.f;
    #pragma unroll
    for (int u = 0; u < 3; ++u) { float t = wsum[u]; if (u < wid4) woff += t; }
    float pr = x + woff - run0;
    #pragma unroll
    for (int k = 0; k < 8; ++k) { pr += wvv[base + k]; pfx[base + k] = pr; }
    __syncthreads();
    for (int i = tid; i < 2046; i += 256) {
      float z = pfx[i] + pfx[2045 - i] - wvv[0];
      zout[(size_t)(i + 1) * 12 + h] = z;
    }
    if (tid == 0) { zout[h] = 0.f; zout[(size_t)2047 * 12 + h] = 0.f; }
    return;
  }

  // ---- transpose: block = (n, h, 128-l chunk). ----
  const int chunk = bx & 15;            // 16 chunks of 128 l
  const int slice = bx >> 4;            // 0..47
  const int n = slice / 12, h = slice - n * 12;
  const int lane = tid & 63;            // d on read side
  const int wv   = tid >> 6;            // 0..3
  const int lbase = chunk * 128 + wv * 32;

  const float* src = v + (((size_t)n * 2048 + lbase) * 12 + h) * 64 + lane;
  #pragma unroll
  for (int kk = 0; kk < 16; ++kk) {
    float f0 = src[(size_t)(2 * kk)     * 768];
    float f1 = src[(size_t)(2 * kk + 1) * 768];
    int l = lbase + 2 * kk;
    unsigned lo = (l == 0)        ? 0u : (unsigned)f2bf(f0);
    unsigned hi = (l + 1 == 2047) ? 0u : (unsigned)f2bf(f1);
    tls[lane * 65 + wv * 16 + kk] = lo | (hi << 16);
  }
  __syncthreads();

  const int r = tid >> 2;               // d-row on store side
  const int m = tid & 3;                // 64B segment within row
  unsigned xbuf[16];
  #pragma unroll
  for (int k = 0; k < 16; ++k) xbuf[k] = tls[r * 65 + m * 16 + k];
  unsigned* dstu = (unsigned*)(g_vt + (((size_t)n * 12 + h) * 64 + r) * 2048 +
                               (size_t)chunk * 128) + m * 16;
  #pragma unroll
  for (int k4 = 0; k4 < 4; ++k4) {
    uint4_ val = {xbuf[k4 * 4], xbuf[k4 * 4 + 1], xbuf[k4 * 4 + 2], xbuf[k4 * 4 + 3]};
    *(uint4_*)&dstu[k4 * 4] = val;
  }
}

// ---------------- dispatch 2: Toeplitz GEMM, 128j x 64nd per block ----------------------
__global__ __launch_bounds__(256, 3) void gemm_kernel(float* __restrict__ out) {
  __shared__ __attribute__((aligned(16))) short Als[2304 * 8];  // 36,864 B

  const int bx  = blockIdx.x;
  const int tid = threadIdx.x;

  const int slice = bx % 48;          // (h, ndt); same-slice blocks 48 apart -> same XCD
  const int jt    = bx / 48;          // 16 j-tiles
  const int ndt = slice & 3;
  const int h   = slice >> 2;
  const int lane = tid & 63;
  const int wid  = tid >> 6;
  const int lm = lane & 15, quad = lane >> 4;
  const int jb = jt * 128;
  const int d  = wid * 16 + lm;       // wave owns a 16-d strip

  // B: bf16 v^T row (borders pre-zeroed). One dwordx4 IS the B-fragment.
  const short* vtb = g_vt + (((size_t)ndt * 12 + h) * 64 + d) * 2048;
  auto load_bf = [&](int lb) -> short8 {
    return *(const short8*)&vtb[lb];
  };

  // prologue B (t=0,1): plain loads, latency hides under the A-window copy
  short8 bc0 = load_bf(quad * 8);
  short8 bc1 = load_bf(32 + quad * 8);
  short8 bn0 = load_bf(64 + quad * 8);
  short8 bn1 = load_bf(96 + quad * 8);

  // copy this block's A-window g_wt[h][qbase .. qbase+2303] -> LDS (coalesced)
  const short* wsrc = g_wt + (size_t)h * QN * 8 + (size_t)(2047 - jb) * 8;
  #pragma unroll
  for (int k = 0; k < 9; ++k) {
    *(short8*)&Als[(size_t)(k * 256 + tid) * 8] =
        *(const short8*)&wsrc[(size_t)(k * 256 + tid) * 8];
  }
  __syncthreads();   // drains vmcnt/lgkmcnt: clean counter state at loop entry

  // A-frag at slot p+abase (16B each): value_i = w_ext[j - k] for this lane's (quad,lm).
  const int abase = 127 + quad * 8 - lm;
  auto load_af = [&](int p) -> short8 {
    return *(const short8*)&Als[(size_t)(p + abase) * 8];
  };

  short8 afr[10];                      // afr[i] = diagonal g = i-7 relative to current l0
  #pragma unroll
  for (int i = 0; i < 10; ++i) afr[i] = load_af((i - 7) * 16);

  floatx4 acc[8];
  #pragma unroll
  for (int ma = 0; ma < 8; ++ma) acc[ma] = (floatx4){0.f, 0.f, 0.f, 0.f};

  // running asm address registers (zero per-iter address VALU beyond 3 adds)
  unsigned az = (unsigned)(unsigned long long)(&Als[(size_t)abase * 8]) + 768u;
                                        // t=0: (l0n-16)*16 = 48*16 = 768
  unsigned long long vb = (unsigned long long)(const void*)(vtb + quad * 8) + 256ull;
                                        // t=0: B bytes for t+2 = (t+2)*128 = 256

  short8 na0, na1, na2, na3, bm0, bm1;

  auto cluster = [&]() {
    __builtin_amdgcn_s_setprio(1);
    #pragma unroll
    for (int ma = 0; ma < 8; ++ma)   // kc=0: g = -ma  -> idx 7-ma
      acc[ma] = __builtin_amdgcn_mfma_f32_16x16x32_bf16(afr[7 - ma], bc0, acc[ma], 0, 0, 0);
    #pragma unroll
    for (int ma = 0; ma < 8; ++ma)   // kc=1: g = 2-ma -> idx 9-ma
      acc[ma] = __builtin_amdgcn_mfma_f32_16x16x32_bf16(afr[9 - ma], bc1, acc[ma], 0, 0, 0);
    __builtin_amdgcn_s_setprio(0);
  };
  auto rotA = [&]() {
    #pragma unroll
    for (int i = 0; i < 6; ++i) afr[i] = afr[i + 4];
    afr[6] = na0; afr[7] = na1; afr[8] = na2; afr[9] = na3;
  };

  #pragma unroll 2
  for (int t = 0; t < 30; ++t) {
    // A(t+1): 4 fresh diagonals g=-1,0,1,2 at (l0n-16..l0n+32)*16 bytes
    asm volatile("ds_read_b128 %0, %1 offset:0"   : "=v"(na0) : "v"(az));
    asm volatile("ds_read_b128 %0, %1 offset:256" : "=v"(na1) : "v"(az));
    asm volatile("ds_read_b128 %0, %1 offset:512" : "=v"(na2) : "v"(az));
    asm volatile("ds_read_b128 %0, %1 offset:768" : "=v"(na3) : "v"(az));
    // B(t+2): two dwordx4, 64B apart
    asm volatile("global_load_dwordx4 %0, %1, off"           : "=v"(bm0) : "v"(vb));
    asm volatile("global_load_dwordx4 %0, %1, off offset:64" : "=v"(bm1) : "v"(vb));
    // counted wait: allow the 4 newest VMEM (t+1,t+2 pairs); bc(t)'s loads are done
    asm volatile("s_waitcnt vmcnt(4)" ::: "memory");
    __builtin_amdgcn_sched_barrier(0);
    cluster();
    asm volatile("s_waitcnt lgkmcnt(0)" ::: "memory");
    __builtin_amdgcn_sched_barrier(0);
    rotA();
    bc0 = bn0; bc1 = bn1;
    bn0 = bm0; bn1 = bm1;
    az += 1024u;
    vb += 128ull;
  }
  // t=30: A(31) fresh, no B issue; bc(30) loaded at t=28 -> vmcnt(2)
  {
    asm volatile("ds_read_b128 %0, %1 offset:0"   : "=v"(na0) : "v"(az));
    asm volatile("ds_read_b128 %0, %1 offset:256" : "=v"(na1) : "v"(az));
    asm volatile("ds_read_b128 %0, %1 offset:512" : "=v"(na2) : "v"(az));
    asm volatile("ds_read_b128 %0, %1 offset:768" : "=v"(na3) : "v"(az));
    asm volatile("s_waitcnt vmcnt(2)" ::: "memory");
    __builtin_amdgcn_sched_barrier(0);
    cluster();
    asm volatile("s_waitcnt lgkmcnt(0)" ::: "memory");
    __builtin_amdgcn_sched_barrier(0);
    rotA();
    bc0 = bn0; bc1 = bn1;
  }
  // t=31: drain
  {
    asm volatile("s_waitcnt vmcnt(0)" ::: "memory");
    __builtin_amdgcn_sched_barrier(0);
    cluster();
  }

  // epilogue: D row = quad*4 + r (j), col = lm (d); zero rows j=0 and j=2047
  float* obase = out + (size_t)ndt * 1572864 + (size_t)h * 64 + d;
  #pragma unroll
  for (int ma = 0; ma < 8; ++ma) {
    floatx4 cc = acc[ma];
    #pragma unroll
    for (int r = 0; r < 4; ++r) {
      int j = jb + ma * 16 + quad * 4 + r;
      float val = (j == 0 || j == 2047) ? 0.f : cc[r];
      obase[(size_t)j * 768] = val;
    }
  }
}

extern "C" void kernel_launch(void* const* d_in, const int* in_sizes, int n_in,
                              void* d_out, int out_size, void* d_ws, size_t ws_size,
                              hipStream_t stream) {
  const float* v = (const float*)d_in[0];   // (4,2048,12,64) fp32
  const float* w = (const float*)d_in[1];   // (12,2048) fp32
  float* out = (float*)d_out;               // pbv (6291456) + z_pb (24576) fp32
  prep_kernel<<<dim3(972), 256, 0, stream>>>(v, w, out);
  gemm_kernel<<<dim3(768), 256, 0, stream>>>(out);
}

// Round 11
// 106.458 us; speedup vs baseline: 1.4128x; 1.0142x over previous
//
#include <hip/hip_runtime.h>
#include <hip/hip_bf16.h>

// PositionalBias: pbv[n,j,h,d] = sum_{l=1..2046} w[h,|j-l|] * v[n,l,h,d]  (j in 1..2046, else 0)
//                 z_pb[l,h]    = sum_{j=1..2046} w[h,|l-j|]               (l in 1..2046, else 0)
// B=4, S=2048, H=12, D=64. Outputs fp32: pbv (6291456) then z_pb (24576).
//
// TWO dispatches (R9/R10 structure; gemm main loop = fully-static asm ring pipeline):
//  1) prep_kernel (972 blocks): 0..767 LDS-transpose v -> g_vt[n][h][d][l] bf16 (borders
//     zeroed); 768..779 z_pb; 780..971 A-fragment table g_wt (12 h x 16 chunks).
//  2) gemm_kernel (768 blocks): A-window LDS copy once, then 32 macro-unrolled iters with
//     COMPILE-TIME ring buffers: afr[16] A-slots (slot = D mod 16, D = 4T+g+7; prefetch
//     slots 4T+10..13 disjoint from window 4T..4T+9 mod 16) and Bp[4] B-pairs (consume
//     T&3, load (T+2)&3). Every asm offset is a literal immediate -> per iter exactly
//     {2 global_load_dwordx4 + 4 ds_read_b128 + 1 s_waitcnt vmcnt(4) lgkmcnt(4) +
//     sched_barrier + 16 MFMA}. ZERO v_mov rotation, ZERO address VALU (R10's loop spent
//     ~58 VALU/iter = ~116 cy/wave on rotation+addressing vs 78 cy of MFMA issue).

typedef short short8 __attribute__((ext_vector_type(8)));   // 8 x bf16 bits (4 VGPRs)
typedef float floatx4 __attribute__((ext_vector_type(4)));  // MFMA accumulator
typedef unsigned uint4_ __attribute__((ext_vector_type(4)));

#define QN 4352   // A-table fragment slots per h; max read = (2047-0)+2303 = 4350

__device__ __attribute__((aligned(16))) short g_vt[4 * 12 * 64 * 2048];  // 12.6 MB
__device__ __attribute__((aligned(16))) short g_wt[12 * QN * 8];         // 835 KB

__device__ __forceinline__ unsigned short f2bf(float f) {
  union { __hip_bfloat16 b; unsigned short u; } cv;
  cv.b = __float2bfloat16(f);  // RNE
  return cv.u;
}

// ---------------- dispatch 1: v -> g_vt (LDS transpose), z_pb, w -> g_wt ----------------
__global__ __launch_bounds__(256) void prep_kernel(const float* __restrict__ v,
                                                   const float* __restrict__ w,
                                                   float* __restrict__ out) {
  __shared__ unsigned tls[64 * 65];   // transpose tile: [d][l-pair], pad->2-way only
  __shared__ float zls[4096];
  __shared__ float wsum[4];

  const int bx  = blockIdx.x;
  const int tid = threadIdx.x;

  if (bx >= 780) {   // ---- A fragment table, 192 blocks: (h, 272-slot chunk) ----
    const int idx = bx - 780;
    const int h = idx >> 4;
    const int c = idx & 15;
    const float* wh = w + (size_t)h * 2048;
    short* F = g_wt + (size_t)h * QN * 8;
    const int qs = c * 272;
    for (int q = qs + tid; q < qs + 272; q += 256) {
      unsigned short buf[8] __attribute__((aligned(16)));
      #pragma unroll
      for (int i = 0; i < 8; ++i) {
        int t = 2174 - q - i;
        int a = t < 0 ? -t : t;
        buf[i] = (a <= 2045) ? f2bf(wh[a]) : (unsigned short)0;
      }
      *(short8*)&F[(size_t)q * 8] = *(const short8*)buf;
    }
    return;
  }

  if (bx >= 768) {   // ---- zpb: z[i+1] = P[i] + P[2045-i] - w[h,0] ----
    const int h = bx - 768;
    float* wvv = zls;          // [2048]
    float* pfx = zls + 2048;   // [2048]
    const float* wh = w + (size_t)h * 2048;
    float* zout = out + 6291456;
    for (int i = tid; i < 2048; i += 256) wvv[i] = (i < 2046) ? wh[i] : 0.f;
    __syncthreads();
    const int base = tid * 8;
    float run0 = 0.f;
    #pragma unroll
    for (int k = 0; k < 8; ++k) run0 += wvv[base + k];
    float x = run0;
    #pragma unroll
    for (int dd = 1; dd < 64; dd <<= 1) {
      float y = __shfl_up(x, dd);
      if ((tid & 63) >= dd) x += y;
    }
    if ((tid & 63) == 63) wsum[tid >> 6] = x;
    __syncthreads();
    const int wid4 = tid >> 6;
    float woff = 0.f;
    #pragma unroll
    for (int u = 0; u < 3; ++u) { float t = wsum[u]; if (u < wid4) woff += t; }
    float pr = x + woff - run0;
    #pragma unroll
    for (int k = 0; k < 8; ++k) { pr += wvv[base + k]; pfx[base + k] = pr; }
    __syncthreads();
    for (int i = tid; i < 2046; i += 256) {
      float z = pfx[i] + pfx[2045 - i] - wvv[0];
      zout[(size_t)(i + 1) * 12 + h] = z;
    }
    if (tid == 0) { zout[h] = 0.f; zout[(size_t)2047 * 12 + h] = 0.f; }
    return;
  }

  // ---- transpose: block = (n, h, 128-l chunk). ----
  const int chunk = bx & 15;            // 16 chunks of 128 l
  const int slice = bx >> 4;            // 0..47
  const int n = slice / 12, h = slice - n * 12;
  const int lane = tid & 63;            // d on read side
  const int wv   = tid >> 6;            // 0..3
  const int lbase = chunk * 128 + wv * 32;

  const float* src = v + (((size_t)n * 2048 + lbase) * 12 + h) * 64 + lane;
  #pragma unroll
  for (int kk = 0; kk < 16; ++kk) {
    float f0 = src[(size_t)(2 * kk)     * 768];
    float f1 = src[(size_t)(2 * kk + 1) * 768];
    int l = lbase + 2 * kk;
    unsigned lo = (l == 0)        ? 0u : (unsigned)f2bf(f0);
    unsigned hi = (l + 1 == 2047) ? 0u : (unsigned)f2bf(f1);
    tls[lane * 65 + wv * 16 + kk] = lo | (hi << 16);
  }
  __syncthreads();

  const int r = tid >> 2;               // d-row on store side
  const int m = tid & 3;                // 64B segment within row
  unsigned xbuf[16];
  #pragma unroll
  for (int k = 0; k < 16; ++k) xbuf[k] = tls[r * 65 + m * 16 + k];
  unsigned* dstu = (unsigned*)(g_vt + (((size_t)n * 12 + h) * 64 + r) * 2048 +
                               (size_t)chunk * 128) + m * 16;
  #pragma unroll
  for (int k4 = 0; k4 < 4; ++k4) {
    uint4_ val = {xbuf[k4 * 4], xbuf[k4 * 4 + 1], xbuf[k4 * 4 + 2], xbuf[k4 * 4 + 3]};
    *(uint4_*)&dstu[k4 * 4] = val;
  }
}

// ---------------- dispatch 2: Toeplitz GEMM, 128j x 64nd per block ----------------------
__global__ __launch_bounds__(256, 3) void gemm_kernel(float* __restrict__ out) {
  __shared__ __attribute__((aligned(16))) short Als[2304 * 8];  // 36,864 B

  const int bx  = blockIdx.x;
  const int tid = threadIdx.x;

  const int slice = bx % 48;          // (h, ndt); same-slice blocks 48 apart -> same XCD
  const int jt    = bx / 48;          // 16 j-tiles
  const int ndt = slice & 3;
  const int h   = slice >> 2;
  const int lane = tid & 63;
  const int wid  = tid >> 6;
  const int lm = lane & 15, quad = lane >> 4;
  const int jb = jt * 128;
  const int d  = wid * 16 + lm;       // wave owns a 16-d strip

  // B: bf16 v^T row (borders pre-zeroed in prep). One dwordx4 IS the B-fragment.
  const short* vtb = g_vt + (((size_t)ndt * 12 + h) * 64 + d) * 2048;

  short8 afr[16];      // A ring: slot = D & 15, D = 4T + g + 7 (prefetch disjoint mod 16)
  short8 Bp0[4], Bp1[4];

  // prologue B pairs t=0,1 (plain loads; drained by the barrier below)
  Bp0[0] = *(const short8*)&vtb[quad * 8];
  Bp1[0] = *(const short8*)&vtb[quad * 8 + 32];
  Bp0[1] = *(const short8*)&vtb[64 + quad * 8];
  Bp1[1] = *(const short8*)&vtb[64 + quad * 8 + 32];

  // copy this block's A-window g_wt[h][qbase .. qbase+2303] -> LDS (coalesced)
  const short* wsrc = g_wt + (size_t)h * QN * 8 + (size_t)(2047 - jb) * 8;
  #pragma unroll
  for (int k = 0; k < 9; ++k) {
    *(short8*)&Als[(size_t)(k * 256 + tid) * 8] =
        *(const short8*)&wsrc[(size_t)(k * 256 + tid) * 8];
  }
  __syncthreads();   // drains vmcnt/lgkmcnt: clean counter state at loop entry

  // A byte address: frag at diagonal D -> az0 + 256*D, az0 = &Als + abase*16 - 1792.
  // abase = 127 + quad*8 - lm >= 112 -> az0 >= LDS base. Max offset 256*133 = 34048.
  const int abase = 127 + quad * 8 - lm;
  unsigned az0 = (unsigned)(unsigned long long)(&Als[0]) + (unsigned)(abase * 16) - 1792u;
  // B base: pair T at vb0 + T*128 (+64 for kc=1). Max literal 31*128+64 = 4032.
  unsigned long long vb0 = (unsigned long long)(const void*)(vtb + quad * 8);

  floatx4 acc[8];
  #pragma unroll
  for (int ma = 0; ma < 8; ++ma) acc[ma] = (floatx4){0.f, 0.f, 0.f, 0.f};

  // prologue A window: D = 0..9 (g = -7..2 at T=0)
#define A_PRO(D) \
  asm volatile("ds_read_b128 %0, %1 offset:%2" : "=v"(afr[D]) : "v"(az0), "n"(256 * (D)));
  A_PRO(0) A_PRO(1) A_PRO(2) A_PRO(3) A_PRO(4)
  A_PRO(5) A_PRO(6) A_PRO(7) A_PRO(8) A_PRO(9)
#undef A_PRO

  // one iteration, T = compile-time literal. Order: issue B(T+2), issue A(T+1),
  // counted wait (newest 4 VMEM + newest 4 LDS may remain), fence, 16 MFMA.
#define G_ITER(T)                                                                        \
  {                                                                                      \
    if ((T) < 30) {                                                                      \
      asm volatile("global_load_dwordx4 %0, %1, off offset:%2"                           \
                   : "=v"(Bp0[((T) + 2) & 3])                                            \
                   : "v"(vb0), "n"((((T) < 30 ? (T) + 2 : 0) * 128)));                   \
      asm volatile("global_load_dwordx4 %0, %1, off offset:%2"                           \
                   : "=v"(Bp1[((T) + 2) & 3])                                            \
                   : "v"(vb0), "n"((((T) < 30 ? (T) + 2 : 0) * 128 + 64)));              \
    }                                                                                    \
    if ((T) < 31) {                                                                      \
      asm volatile("ds_read_b128 %0, %1 offset:%2"                                       \
                   : "=v"(afr[(4 * (T) + 10) & 15])                                      \
                   : "v"(az0), "n"(((T) < 31 ? 1024 * (T) + 2560 : 0)));                 \
      asm volatile("ds_read_b128 %0, %1 offset:%2"                                       \
                   : "=v"(afr[(4 * (T) + 11) & 15])                                      \
                   : "v"(az0), "n"(((T) < 31 ? 1024 * (T) + 2816 : 0)));                 \
      asm volatile("ds_read_b128 %0, %1 offset:%2"                                       \
                   : "=v"(afr[(4 * (T) + 12) & 15])                                      \
                   : "v"(az0), "n"(((T) < 31 ? 1024 * (T) + 3072 : 0)));                 \
      asm volatile("ds_read_b128 %0, %1 offset:%2"                                       \
                   : "=v"(afr[(4 * (T) + 13) & 15])                                      \
                   : "v"(az0), "n"(((T) < 31 ? 1024 * (T) + 3328 : 0)));                 \
    }                                                                                    \
    if ((T) < 30)       asm volatile("s_waitcnt vmcnt(4) lgkmcnt(4)" ::: "memory");      \
    else if ((T) == 30) asm volatile("s_waitcnt vmcnt(2) lgkmcnt(4)" ::: "memory");      \
    else                asm volatile("s_waitcnt vmcnt(0) lgkmcnt(0)" ::: "memory");      \
    __builtin_amdgcn_sched_barrier(0);                                                   \
    __builtin_amdgcn_s_setprio(1);                                                       \
    _Pragma("unroll")                                                                    \
    for (int ma = 0; ma < 8; ++ma)  /* kc=0: g=-ma -> D=4T+7-ma */                       \
      acc[ma] = __builtin_amdgcn_mfma_f32_16x16x32_bf16(                                 \
          afr[(4 * (T) + 7 - ma) & 15], Bp0[(T) & 3], acc[ma], 0, 0, 0);                 \
    _Pragma("unroll")                                                                    \
    for (int ma = 0; ma < 8; ++ma)  /* kc=1: g=2-ma -> D=4T+9-ma */                      \
      acc[ma] = __builtin_amdgcn_mfma_f32_16x16x32_bf16(                                 \
          afr[(4 * (T) + 9 - ma) & 15], Bp1[(T) & 3], acc[ma], 0, 0, 0);                 \
    __builtin_amdgcn_s_setprio(0);                                                       \
  }

  G_ITER(0)  G_ITER(1)  G_ITER(2)  G_ITER(3)  G_ITER(4)  G_ITER(5)  G_ITER(6)  G_ITER(7)
  G_ITER(8)  G_ITER(9)  G_ITER(10) G_ITER(11) G_ITER(12) G_ITER(13) G_ITER(14) G_ITER(15)
  G_ITER(16) G_ITER(17) G_ITER(18) G_ITER(19) G_ITER(20) G_ITER(21) G_ITER(22) G_ITER(23)
  G_ITER(24) G_ITER(25) G_ITER(26) G_ITER(27) G_ITER(28) G_ITER(29) G_ITER(30) G_ITER(31)
#undef G_ITER

  // epilogue: D row = quad*4 + r (j), col = lm (d); zero rows j=0 and j=2047
  float* obase = out + (size_t)ndt * 1572864 + (size_t)h * 64 + d;
  #pragma unroll
  for (int ma = 0; ma < 8; ++ma) {
    floatx4 cc = acc[ma];
    #pragma unroll
    for (int r = 0; r < 4; ++r) {
      int j = jb + ma * 16 + quad * 4 + r;
      float val = (j == 0 || j == 2047) ? 0.f : cc[r];
      obase[(size_t)j * 768] = val;
    }
  }
}

extern "C" void kernel_launch(void* const* d_in, const int* in_sizes, int n_in,
                              void* d_out, int out_size, void* d_ws, size_t ws_size,
                              hipStream_t stream) {
  const float* v = (const float*)d_in[0];   // (4,2048,12,64) fp32
  const float* w = (const float*)d_in[1];   // (12,2048) fp32
  float* out = (float*)d_out;               // pbv (6291456) + z_pb (24576) fp32
  prep_kernel<<<dim3(972), 256, 0, stream>>>(v, w, out);
  gemm_kernel<<<dim3(768), 256, 0, stream>>>(out);
}